// Round 1
// baseline (478.656 us; speedup 1.0000x reference)
//
#include <hip/hip_runtime.h>
#include <hip/hip_bf16.h>

typedef __attribute__((ext_vector_type(8))) short short8;
typedef __attribute__((ext_vector_type(4))) float floatx4;

#define LOG2E 1.4426950408889634f

static __device__ __forceinline__ short f2bf(float f) {
    unsigned int u = __float_as_uint(f);
    unsigned int r = u + 0x7FFFu + ((u >> 16) & 1u);
    return (short)(r >> 16);
}
static __device__ __forceinline__ float bf2f(short s) {
    return __uint_as_float(((unsigned int)(unsigned short)s) << 16);
}

// ---------------- transpose + cast f32 [R][C] -> bf16 [C][R] ----------------
__global__ void transpose_cast_kernel(const float* __restrict__ in,
                                      short* __restrict__ out, int R, int C) {
    __shared__ float tile[32][33];
    const int tx = threadIdx.x, ty = threadIdx.y;
    const int x = blockIdx.x * 32 + tx;
    const int y0 = blockIdx.y * 32;
#pragma unroll
    for (int j = 0; j < 4; ++j)
        tile[ty + j * 8][tx] = in[(size_t)(y0 + ty + j * 8) * C + x];
    __syncthreads();
#pragma unroll
    for (int j = 0; j < 4; ++j)
        out[(size_t)(blockIdx.x * 32 + ty + j * 8) * R + y0 + tx] =
            f2bf(tile[tx][ty + j * 8]);
}

// ---------------- GEMM: A[M,K] x Bt[N,K] -> C[M,N] (+bias) ----------------
// AF32: A operand is f32 (cast to bf16 during staging). EPI: 0 = scatter QKV, 1 = f32 out.
template <int AF32, int EPI>
__global__ __launch_bounds__(256) void gemm_bt_kernel(
    const void* __restrict__ Aptr, const short* __restrict__ Bt,
    const float* __restrict__ bias, float* __restrict__ Cf,
    short* __restrict__ Qb, short* __restrict__ Kb, short* __restrict__ Vt,
    int M, int N, int K) {
    __shared__ __align__(16) short As[128][40];
    __shared__ __align__(16) short Bs[128][40];

    const int tid = threadIdx.x;
    const int lane = tid & 63, wave = tid >> 6;
    const int wm = wave >> 1, wn = wave & 1;
    const int lr = lane & 15, lk = lane >> 4;
    const int bm0 = blockIdx.y * 128, bn0 = blockIdx.x * 128;

    floatx4 acc[4][4];
#pragma unroll
    for (int m = 0; m < 4; ++m)
#pragma unroll
        for (int n = 0; n < 4; ++n) acc[m][n] = (floatx4){0.f, 0.f, 0.f, 0.f};

    const int ar = tid >> 1;            // 0..127 staging row
    const int ac = (tid & 1) * 16;      // 0 or 16 (k chunk)

    for (int k0 = 0; k0 < K; k0 += 32) {
        __syncthreads();
        // ---- stage A tile 128x32 ----
        if (AF32) {
            const float* Ag = (const float*)Aptr + (size_t)(bm0 + ar) * K + k0 + ac;
            float4 v0 = *(const float4*)(Ag + 0);
            float4 v1 = *(const float4*)(Ag + 4);
            float4 v2 = *(const float4*)(Ag + 8);
            float4 v3 = *(const float4*)(Ag + 12);
            short8 s0, s1;
            s0[0] = f2bf(v0.x); s0[1] = f2bf(v0.y); s0[2] = f2bf(v0.z); s0[3] = f2bf(v0.w);
            s0[4] = f2bf(v1.x); s0[5] = f2bf(v1.y); s0[6] = f2bf(v1.z); s0[7] = f2bf(v1.w);
            s1[0] = f2bf(v2.x); s1[1] = f2bf(v2.y); s1[2] = f2bf(v2.z); s1[3] = f2bf(v2.w);
            s1[4] = f2bf(v3.x); s1[5] = f2bf(v3.y); s1[6] = f2bf(v3.z); s1[7] = f2bf(v3.w);
            *(short8*)&As[ar][ac] = s0;
            *(short8*)&As[ar][ac + 8] = s1;
        } else {
            const short* Ag = (const short*)Aptr + (size_t)(bm0 + ar) * K + k0 + ac;
            *(short8*)&As[ar][ac] = *(const short8*)(Ag);
            *(short8*)&As[ar][ac + 8] = *(const short8*)(Ag + 8);
        }
        // ---- stage B tile 128x32 (Bt rows are K-contiguous) ----
        {
            const short* Bg = Bt + (size_t)(bn0 + ar) * K + k0 + ac;
            *(short8*)&Bs[ar][ac] = *(const short8*)(Bg);
            *(short8*)&Bs[ar][ac + 8] = *(const short8*)(Bg + 8);
        }
        __syncthreads();
        // ---- compute ----
        short8 af[4], bfr[4];
#pragma unroll
        for (int m = 0; m < 4; ++m)
            af[m] = *(const short8*)&As[wm * 64 + m * 16 + lr][lk * 8];
#pragma unroll
        for (int n = 0; n < 4; ++n)
            bfr[n] = *(const short8*)&Bs[wn * 64 + n * 16 + lr][lk * 8];
#pragma unroll
        for (int m = 0; m < 4; ++m)
#pragma unroll
            for (int n = 0; n < 4; ++n)
                acc[m][n] = __builtin_amdgcn_mfma_f32_16x16x32_bf16(
                    af[m], bfr[n], acc[m][n], 0, 0, 0);
    }

    // ---- epilogue ----
#pragma unroll
    for (int m = 0; m < 4; ++m)
#pragma unroll
        for (int n = 0; n < 4; ++n)
#pragma unroll
            for (int r = 0; r < 4; ++r) {
                const int row = bm0 + wm * 64 + m * 16 + lk * 4 + r;
                const int col = bn0 + wn * 64 + n * 16 + lr;
                const float val = acc[m][n][r] + bias[col];
                if (EPI == 1) {
                    Cf[(size_t)row * N + col] = val;
                } else {
                    const short bv = f2bf(val);
                    const int t = col >> 11, h = (col >> 7) & 15, dq = col & 127;
                    const int b = row >> 11, s = row & 2047;
                    if (t == 0)
                        Qb[(((size_t)(b * 16 + h)) * 2048 + s) * 128 + dq] = bv;
                    else if (t == 1)
                        Kb[(((size_t)(b * 16 + h)) * 2048 + s) * 128 + dq] = bv;
                    else
                        Vt[(((size_t)(b * 16 + h)) * 128 + dq) * 2048 + s] = bv;
                }
            }
}

// ---------------- RoPE (in-place on bf16 Q and K, [B,H,S,DQ]) ----------------
__global__ void rope_kernel(short* __restrict__ Qb, short* __restrict__ Kb,
                            const int* __restrict__ pos, int total) {
    int i = blockIdx.x * blockDim.x + threadIdx.x;
    short* T = Qb;
    int j = i;
    if (i >= total) { T = Kb; j = i - total; }
    if (j >= total) return;
    const int ih = j & 63;
    const int s = (j >> 6) & 2047;
    const size_t base = ((size_t)(j >> 6)) * 128 + ih;
    const float t1 = bf2f(T[base]);
    const float t2 = bf2f(T[base + 64]);
    const float p = (float)pos[s];
    // inv_freq = 10000^(-ih/64) = 2^(-ih*log2(10000)/64)
    const float ang = p * exp2f((float)ih * (-13.287712379549449f / 64.0f));
    float sn, cs;
    sincosf(ang, &sn, &cs);
    T[base] = f2bf(t1 * cs - t2 * sn);
    T[base + 64] = f2bf(t1 * sn + t2 * cs);
}

// ---------------- causal flash attention ----------------
// grid: (S/64, B*H). 4 waves, each owns 16 q-rows. KV tiles of 64.
__global__ __launch_bounds__(256) void attn_kernel(
    const short* __restrict__ Qb, const short* __restrict__ Kb,
    const short* __restrict__ Vt, short* __restrict__ Ob) {
    const int qt = blockIdx.x;
    const int bh = blockIdx.y;
    const int wave = threadIdx.x >> 6, lane = threadIdx.x & 63;
    const int lr = lane & 15, lk = lane >> 4;
    const int q0 = qt * 64;
    const short* Qh = Qb + (size_t)bh * 2048 * 128;
    const short* Kh = Kb + (size_t)bh * 2048 * 128;
    const short* Vh = Vt + (size_t)bh * 128 * 2048;

    __shared__ __align__(16) short Ks[64][136];
    __shared__ __align__(16) short Vs[128][72];
    __shared__ __align__(16) short Ps[4][16][72];

    short8 qf[4];
#pragma unroll
    for (int kc = 0; kc < 4; ++kc)
        qf[kc] = *(const short8*)&Qh[(size_t)(q0 + wave * 16 + lr) * 128 + kc * 32 + lk * 8];

    floatx4 o[8];
#pragma unroll
    for (int d = 0; d < 8; ++d) o[d] = (floatx4){0.f, 0.f, 0.f, 0.f};
    float mrow[4], lrow[4];
#pragma unroll
    for (int r = 0; r < 4; ++r) { mrow[r] = -__builtin_inff(); lrow[r] = 0.f; }

    const float scale = 0.08838834764831845f;  // 1/sqrt(128)
    const int ntile = qt + 1;

    for (int t = 0; t < ntile; ++t) {
        const int s0 = t * 64;
        __syncthreads();
        {   // stage K tile [64][128]
            const int r = threadIdx.x >> 2, c = (threadIdx.x & 3) * 32;
            const short* src = Kh + (size_t)(s0 + r) * 128 + c;
#pragma unroll
            for (int i = 0; i < 4; ++i)
                *(short8*)&Ks[r][c + i * 8] = *(const short8*)(src + i * 8);
        }
        {   // stage Vt tile [128][64]
            const int r = threadIdx.x >> 1, c = (threadIdx.x & 1) * 32;
            const short* src = Vh + (size_t)r * 2048 + s0 + c;
#pragma unroll
            for (int i = 0; i < 4; ++i)
                *(short8*)&Vs[r][c + i * 8] = *(const short8*)(src + i * 8);
        }
        __syncthreads();

        // ---- S = Q K^T (scaled) ----
        floatx4 sv[4];
#pragma unroll
        for (int nt = 0; nt < 4; ++nt) {
            floatx4 a = (floatx4){0.f, 0.f, 0.f, 0.f};
#pragma unroll
            for (int kc = 0; kc < 4; ++kc) {
                short8 kf = *(const short8*)&Ks[nt * 16 + lr][kc * 32 + lk * 8];
                a = __builtin_amdgcn_mfma_f32_16x16x32_bf16(qf[kc], kf, a, 0, 0, 0);
            }
            sv[nt] = a;
        }

        const bool diag = (s0 == q0);
#pragma unroll
        for (int nt = 0; nt < 4; ++nt)
#pragma unroll
            for (int r = 0; r < 4; ++r) {
                float x = sv[nt][r] * scale;
                if (diag) {
                    const int col = s0 + nt * 16 + lr;
                    const int row = q0 + wave * 16 + lk * 4 + r;
                    if (col > row) x = -__builtin_inff();
                }
                sv[nt][r] = x;
            }

        // ---- online softmax ----
        float mnew[4], alpha[4];
#pragma unroll
        for (int r = 0; r < 4; ++r) {
            float tm = fmaxf(fmaxf(sv[0][r], sv[1][r]), fmaxf(sv[2][r], sv[3][r]));
            tm = fmaxf(tm, __shfl_xor(tm, 1));
            tm = fmaxf(tm, __shfl_xor(tm, 2));
            tm = fmaxf(tm, __shfl_xor(tm, 4));
            tm = fmaxf(tm, __shfl_xor(tm, 8));
            const float mn = fmaxf(mrow[r], tm);
            alpha[r] = exp2f((mrow[r] - mn) * LOG2E);
            mnew[r] = mn;
            mrow[r] = mn;
        }
#pragma unroll
        for (int r = 0; r < 4; ++r) {
            float rs = 0.f;
#pragma unroll
            for (int nt = 0; nt < 4; ++nt) {
                const float p = exp2f((sv[nt][r] - mnew[r]) * LOG2E);
                sv[nt][r] = p;
                rs += p;
            }
            rs += __shfl_xor(rs, 1);
            rs += __shfl_xor(rs, 2);
            rs += __shfl_xor(rs, 4);
            rs += __shfl_xor(rs, 8);
            lrow[r] = lrow[r] * alpha[r] + rs;
        }
#pragma unroll
        for (int d = 0; d < 8; ++d)
#pragma unroll
            for (int r = 0; r < 4; ++r) o[d][r] *= alpha[r];

        // ---- P (C-layout) -> LDS -> A-layout frags ----
#pragma unroll
        for (int nt = 0; nt < 4; ++nt)
#pragma unroll
            for (int r = 0; r < 4; ++r)
                Ps[wave][lk * 4 + r][nt * 16 + lr] = f2bf(sv[nt][r]);
        __syncthreads();

        // ---- O += P V ----
#pragma unroll
        for (int kc = 0; kc < 2; ++kc) {
            short8 pf = *(const short8*)&Ps[wave][lr][kc * 32 + lk * 8];
#pragma unroll
            for (int d = 0; d < 8; ++d) {
                short8 vf = *(const short8*)&Vs[d * 16 + lr][kc * 32 + lk * 8];
                o[d] = __builtin_amdgcn_mfma_f32_16x16x32_bf16(pf, vf, o[d], 0, 0, 0);
            }
        }
    }

    // ---- epilogue: O/l -> attn_concat [B,S,H*DQ] bf16 ----
    const int b = bh >> 4, h = bh & 15;
#pragma unroll
    for (int d = 0; d < 8; ++d)
#pragma unroll
        for (int r = 0; r < 4; ++r) {
            const int srow = q0 + wave * 16 + lk * 4 + r;
            const float val = o[d][r] / lrow[r];
            Ob[((size_t)(b * 2048 + srow)) * 2048 + h * 128 + d * 16 + lr] = f2bf(val);
        }
}

extern "C" void kernel_launch(void* const* d_in, const int* in_sizes, int n_in,
                              void* d_out, int out_size, void* d_ws, size_t ws_size,
                              hipStream_t stream) {
    const float* x = (const float*)d_in[0];
    const int* rope_pos = (const int*)d_in[1];
    const float* W_qkv = (const float*)d_in[2];
    const float* b_qkv = (const float*)d_in[3];
    const float* W_out = (const float*)d_in[4];
    const float* b_out = (const float*)d_in[5];
    float* out = (float*)d_out;

    char* ws = (char*)d_ws;
    short* Wqkvt = (short*)ws;                                   // 6144*2048 bf16 = 25165824 B
    short* Woutt = (short*)(ws + 25165824);                      // 2048*2048 bf16 = 8388608 B
    short* Qb = (short*)(ws + 25165824 + 8388608);               // 32*2048*128 bf16
    short* Kb = Qb + 8388608;
    short* Vt = Kb + 8388608;
    short* Attn = Vt + 8388608;

    transpose_cast_kernel<<<dim3(6144 / 32, 2048 / 32), dim3(32, 8), 0, stream>>>(
        W_qkv, Wqkvt, 2048, 6144);
    transpose_cast_kernel<<<dim3(2048 / 32, 2048 / 32), dim3(32, 8), 0, stream>>>(
        W_out, Woutt, 2048, 2048);
    gemm_bt_kernel<1, 0><<<dim3(48, 32), 256, 0, stream>>>(
        (const void*)x, Wqkvt, b_qkv, nullptr, Qb, Kb, Vt, 4096, 6144, 2048);
    rope_kernel<<<32768, 256, 0, stream>>>(Qb, Kb, rope_pos, 4194304);
    attn_kernel<<<dim3(32, 32), 256, 0, stream>>>(Qb, Kb, Vt, Attn);
    gemm_bt_kernel<0, 1><<<dim3(16, 32), 256, 0, stream>>>(
        (const void*)Attn, Woutt, b_out, out, nullptr, nullptr, nullptr, 4096, 2048, 2048);
}

// Round 2
// 447.765 us; speedup vs baseline: 1.0690x; 1.0690x over previous
//
#include <hip/hip_runtime.h>
#include <hip/hip_bf16.h>

typedef __attribute__((ext_vector_type(8))) short short8;
typedef __attribute__((ext_vector_type(4))) float floatx4;

#define LOG2E 1.4426950408889634f

static __device__ __forceinline__ short f2bf(float f) {
    unsigned int u = __float_as_uint(f);
    unsigned int r = u + 0x7FFFu + ((u >> 16) & 1u);
    return (short)(r >> 16);
}
static __device__ __forceinline__ float bf2f(short s) {
    return __uint_as_float(((unsigned int)(unsigned short)s) << 16);
}

static __device__ __forceinline__ void load_lds16(const void* g, void* l) {
    __builtin_amdgcn_global_load_lds(
        (const __attribute__((address_space(1))) unsigned int*)g,
        (__attribute__((address_space(3))) unsigned int*)l, 16, 0, 0);
}

// ---------------- cast f32 -> bf16 (8 elems/thread) ----------------
__global__ void cast_f32_bf16_kernel(const float* __restrict__ in,
                                     short* __restrict__ out, int n8) {
    const int i = blockIdx.x * blockDim.x + threadIdx.x;
    if (i >= n8) return;
    const float4 v0 = *(const float4*)(in + (size_t)i * 8);
    const float4 v1 = *(const float4*)(in + (size_t)i * 8 + 4);
    short8 s;
    s[0] = f2bf(v0.x); s[1] = f2bf(v0.y); s[2] = f2bf(v0.z); s[3] = f2bf(v0.w);
    s[4] = f2bf(v1.x); s[5] = f2bf(v1.y); s[6] = f2bf(v1.z); s[7] = f2bf(v1.w);
    *(short8*)(out + (size_t)i * 8) = s;
}

// ---------------- transpose + cast f32 [R][C] -> bf16 [C][R] ----------------
__global__ void transpose_cast_kernel(const float* __restrict__ in,
                                      short* __restrict__ out, int R, int C) {
    __shared__ float tile[32][33];
    const int tx = threadIdx.x, ty = threadIdx.y;
    const int x = blockIdx.x * 32 + tx;
    const int y0 = blockIdx.y * 32;
#pragma unroll
    for (int j = 0; j < 4; ++j)
        tile[ty + j * 8][tx] = in[(size_t)(y0 + ty + j * 8) * C + x];
    __syncthreads();
#pragma unroll
    for (int j = 0; j < 4; ++j)
        out[(size_t)(blockIdx.x * 32 + ty + j * 8) * R + y0 + tx] =
            f2bf(tile[tx][ty + j * 8]);
}

// ---------------- GEMM (m97 structure): A[M,K] x Bt[N,K] -> C[M,N] (+bias) ----------------
// EPI: 0 = scatter QKV epilogue, 1 = f32 output.
// 128x128 tile, BK=32, linear LDS staged via global_load_lds width=16.
template <int EPI>
__global__ __launch_bounds__(256) void gemm97_kernel(
    const short* __restrict__ A, const short* __restrict__ Bt,
    const float* __restrict__ bias, float* __restrict__ Cf,
    short* __restrict__ Qb, short* __restrict__ Kb, short* __restrict__ Vt,
    int M, int N, int K, int gx) {
    __shared__ __align__(16) short As[128 * 32];
    __shared__ __align__(16) short Bs[128 * 32];

    const int tid = threadIdx.x;
    const int lane = tid & 63, wave = tid >> 6;
    const int wm = wave >> 1, wn = wave & 1;
    const int lr = lane & 15, lk = lane >> 4;

    // bijective XCD swizzle (grid sizes here are multiples of 8)
    const int nwg = gridDim.x;
    const int id = blockIdx.x;
    const int swz = (id & 7) * (nwg >> 3) + (id >> 3);
    const int bx = swz % gx, by = swz / gx;
    const int bm0 = by * 128, bn0 = bx * 128;

    // staging geometry: chunk = i*4+wave covers rows [chunk*16, chunk*16+16)
    const int srow = lane >> 2;          // 0..15 within chunk
    const int scol = (lane & 3) * 8;     // 0,8,16,24

    floatx4 acc[4][4];
#pragma unroll
    for (int m = 0; m < 4; ++m)
#pragma unroll
        for (int n = 0; n < 4; ++n) acc[m][n] = (floatx4){0.f, 0.f, 0.f, 0.f};

    for (int k0 = 0; k0 < K; k0 += 32) {
        __syncthreads();
#pragma unroll
        for (int i = 0; i < 2; ++i) {
            const int chunk = i * 4 + wave;
            load_lds16(A + (size_t)(bm0 + chunk * 16 + srow) * K + k0 + scol,
                       As + chunk * 512);
            load_lds16(Bt + (size_t)(bn0 + chunk * 16 + srow) * K + k0 + scol,
                       Bs + chunk * 512);
        }
        __syncthreads();

        short8 af[4], bfr[4];
#pragma unroll
        for (int m = 0; m < 4; ++m)
            af[m] = *(const short8*)&As[(wm * 64 + m * 16 + lr) * 32 + lk * 8];
#pragma unroll
        for (int n = 0; n < 4; ++n)
            bfr[n] = *(const short8*)&Bs[(wn * 64 + n * 16 + lr) * 32 + lk * 8];
#pragma unroll
        for (int m = 0; m < 4; ++m)
#pragma unroll
            for (int n = 0; n < 4; ++n)
                acc[m][n] = __builtin_amdgcn_mfma_f32_16x16x32_bf16(
                    af[m], bfr[n], acc[m][n], 0, 0, 0);
    }

    // ---- epilogue ----
#pragma unroll
    for (int m = 0; m < 4; ++m)
#pragma unroll
        for (int n = 0; n < 4; ++n)
#pragma unroll
            for (int r = 0; r < 4; ++r) {
                const int row = bm0 + wm * 64 + m * 16 + lk * 4 + r;
                const int col = bn0 + wn * 64 + n * 16 + lr;
                const float val = acc[m][n][r] + bias[col];
                if (EPI == 1) {
                    Cf[(size_t)row * N + col] = val;
                } else {
                    const short bv = f2bf(val);
                    const int t = col >> 11, h = (col >> 7) & 15, dq = col & 127;
                    const int b = row >> 11, s = row & 2047;
                    if (t == 0)
                        Qb[(((size_t)(b * 16 + h)) * 2048 + s) * 128 + dq] = bv;
                    else if (t == 1)
                        Kb[(((size_t)(b * 16 + h)) * 2048 + s) * 128 + dq] = bv;
                    else
                        Vt[(((size_t)(b * 16 + h)) * 128 + dq) * 2048 + s] = bv;
                }
            }
}

// ---------------- RoPE (in-place on bf16 Q and K, [B,H,S,DQ]) ----------------
__global__ void rope_kernel(short* __restrict__ Qb, short* __restrict__ Kb,
                            const int* __restrict__ pos, int total) {
    int i = blockIdx.x * blockDim.x + threadIdx.x;
    short* T = Qb;
    int j = i;
    if (i >= total) { T = Kb; j = i - total; }
    if (j >= total) return;
    const int ih = j & 63;
    const int s = (j >> 6) & 2047;
    const size_t base = ((size_t)(j >> 6)) * 128 + ih;
    const float t1 = bf2f(T[base]);
    const float t2 = bf2f(T[base + 64]);
    const float p = (float)pos[s];
    const float ang = p * exp2f((float)ih * (-13.287712379549449f / 64.0f));
    float sn, cs;
    sincosf(ang, &sn, &cs);
    T[base] = f2bf(t1 * cs - t2 * sn);
    T[base + 64] = f2bf(t1 * sn + t2 * cs);
}

// ---------------- causal flash attention ----------------
// grid: (S/64, B*H). 4 waves, each owns 16 q-rows. KV tiles of 64.
__global__ __launch_bounds__(256) void attn_kernel(
    const short* __restrict__ Qb, const short* __restrict__ Kb,
    const short* __restrict__ Vt, short* __restrict__ Ob) {
    const int qt = blockIdx.x;
    const int bh = blockIdx.y;
    const int wave = threadIdx.x >> 6, lane = threadIdx.x & 63;
    const int lr = lane & 15, lk = lane >> 4;
    const int q0 = qt * 64;
    const short* Qh = Qb + (size_t)bh * 2048 * 128;
    const short* Kh = Kb + (size_t)bh * 2048 * 128;
    const short* Vh = Vt + (size_t)bh * 128 * 2048;

    __shared__ __align__(16) short Ks[64][136];
    __shared__ __align__(16) short Vs[128][72];
    __shared__ __align__(16) short Ps[4][16][72];

    short8 qf[4];
#pragma unroll
    for (int kc = 0; kc < 4; ++kc)
        qf[kc] = *(const short8*)&Qh[(size_t)(q0 + wave * 16 + lr) * 128 + kc * 32 + lk * 8];

    floatx4 o[8];
#pragma unroll
    for (int d = 0; d < 8; ++d) o[d] = (floatx4){0.f, 0.f, 0.f, 0.f};
    float mrow[4], lrow[4];
#pragma unroll
    for (int r = 0; r < 4; ++r) { mrow[r] = -__builtin_inff(); lrow[r] = 0.f; }

    const float scale = 0.08838834764831845f;  // 1/sqrt(128)
    const int ntile = qt + 1;

    for (int t = 0; t < ntile; ++t) {
        const int s0 = t * 64;
        __syncthreads();
        {   // stage K tile [64][128]
            const int r = threadIdx.x >> 2, c = (threadIdx.x & 3) * 32;
            const short* src = Kh + (size_t)(s0 + r) * 128 + c;
#pragma unroll
            for (int i = 0; i < 4; ++i)
                *(short8*)&Ks[r][c + i * 8] = *(const short8*)(src + i * 8);
        }
        {   // stage Vt tile [128][64]
            const int r = threadIdx.x >> 1, c = (threadIdx.x & 1) * 32;
            const short* src = Vh + (size_t)r * 2048 + s0 + c;
#pragma unroll
            for (int i = 0; i < 4; ++i)
                *(short8*)&Vs[r][c + i * 8] = *(const short8*)(src + i * 8);
        }
        __syncthreads();

        // ---- S = Q K^T (scaled) ----
        floatx4 sv[4];
#pragma unroll
        for (int nt = 0; nt < 4; ++nt) {
            floatx4 a = (floatx4){0.f, 0.f, 0.f, 0.f};
#pragma unroll
            for (int kc = 0; kc < 4; ++kc) {
                short8 kf = *(const short8*)&Ks[nt * 16 + lr][kc * 32 + lk * 8];
                a = __builtin_amdgcn_mfma_f32_16x16x32_bf16(qf[kc], kf, a, 0, 0, 0);
            }
            sv[nt] = a;
        }

        const bool diag = (s0 == q0);
#pragma unroll
        for (int nt = 0; nt < 4; ++nt)
#pragma unroll
            for (int r = 0; r < 4; ++r) {
                float x = sv[nt][r] * scale;
                if (diag) {
                    const int col = s0 + nt * 16 + lr;
                    const int row = q0 + wave * 16 + lk * 4 + r;
                    if (col > row) x = -__builtin_inff();
                }
                sv[nt][r] = x;
            }

        // ---- online softmax ----
        float mnew[4], alpha[4];
#pragma unroll
        for (int r = 0; r < 4; ++r) {
            float tm = fmaxf(fmaxf(sv[0][r], sv[1][r]), fmaxf(sv[2][r], sv[3][r]));
            tm = fmaxf(tm, __shfl_xor(tm, 1));
            tm = fmaxf(tm, __shfl_xor(tm, 2));
            tm = fmaxf(tm, __shfl_xor(tm, 4));
            tm = fmaxf(tm, __shfl_xor(tm, 8));
            const float mn = fmaxf(mrow[r], tm);
            alpha[r] = exp2f((mrow[r] - mn) * LOG2E);
            mnew[r] = mn;
            mrow[r] = mn;
        }
#pragma unroll
        for (int r = 0; r < 4; ++r) {
            float rs = 0.f;
#pragma unroll
            for (int nt = 0; nt < 4; ++nt) {
                const float p = exp2f((sv[nt][r] - mnew[r]) * LOG2E);
                sv[nt][r] = p;
                rs += p;
            }
            rs += __shfl_xor(rs, 1);
            rs += __shfl_xor(rs, 2);
            rs += __shfl_xor(rs, 4);
            rs += __shfl_xor(rs, 8);
            lrow[r] = lrow[r] * alpha[r] + rs;
        }
#pragma unroll
        for (int d = 0; d < 8; ++d)
#pragma unroll
            for (int r = 0; r < 4; ++r) o[d][r] *= alpha[r];

        // ---- P (C-layout) -> LDS -> A-layout frags ----
#pragma unroll
        for (int nt = 0; nt < 4; ++nt)
#pragma unroll
            for (int r = 0; r < 4; ++r)
                Ps[wave][lk * 4 + r][nt * 16 + lr] = f2bf(sv[nt][r]);
        __syncthreads();

        // ---- O += P V ----
#pragma unroll
        for (int kc = 0; kc < 2; ++kc) {
            short8 pf = *(const short8*)&Ps[wave][lr][kc * 32 + lk * 8];
#pragma unroll
            for (int d = 0; d < 8; ++d) {
                short8 vf = *(const short8*)&Vs[d * 16 + lr][kc * 32 + lk * 8];
                o[d] = __builtin_amdgcn_mfma_f32_16x16x32_bf16(pf, vf, o[d], 0, 0, 0);
            }
        }
    }

    // ---- epilogue: O/l -> attn_concat [B,S,H*DQ] bf16 ----
    const int b = bh >> 4, h = bh & 15;
#pragma unroll
    for (int d = 0; d < 8; ++d)
#pragma unroll
        for (int r = 0; r < 4; ++r) {
            const int srow = q0 + wave * 16 + lk * 4 + r;
            const float val = o[d][r] / lrow[r];
            Ob[((size_t)(b * 2048 + srow)) * 2048 + h * 128 + d * 16 + lr] = f2bf(val);
        }
}

extern "C" void kernel_launch(void* const* d_in, const int* in_sizes, int n_in,
                              void* d_out, int out_size, void* d_ws, size_t ws_size,
                              hipStream_t stream) {
    const float* x = (const float*)d_in[0];
    const int* rope_pos = (const int*)d_in[1];
    const float* W_qkv = (const float*)d_in[2];
    const float* b_qkv = (const float*)d_in[3];
    const float* W_out = (const float*)d_in[4];
    const float* b_out = (const float*)d_in[5];
    float* out = (float*)d_out;

    char* ws = (char*)d_ws;
    short* Wqkvt = (short*)ws;                                   // 6144*2048 bf16 = 25165824 B
    short* Woutt = (short*)(ws + 25165824);                      // 2048*2048 bf16 = 8388608 B
    short* Qb = (short*)(ws + 25165824 + 8388608);               // 32*2048*128 bf16 each
    short* Kb = Qb + 8388608;
    short* Vt = Kb + 8388608;
    short* Attn = Vt + 8388608;
    short* Xb = Attn;  // alias: Xb dead before attn_kernel writes Attn

    cast_f32_bf16_kernel<<<4096, 256, 0, stream>>>(x, Xb, 1048576);
    transpose_cast_kernel<<<dim3(6144 / 32, 2048 / 32), dim3(32, 8), 0, stream>>>(
        W_qkv, Wqkvt, 2048, 6144);
    transpose_cast_kernel<<<dim3(2048 / 32, 2048 / 32), dim3(32, 8), 0, stream>>>(
        W_out, Woutt, 2048, 2048);
    gemm97_kernel<0><<<1536, 256, 0, stream>>>(
        Xb, Wqkvt, b_qkv, nullptr, Qb, Kb, Vt, 4096, 6144, 2048, 48);
    rope_kernel<<<32768, 256, 0, stream>>>(Qb, Kb, rope_pos, 4194304);
    attn_kernel<<<dim3(32, 32), 256, 0, stream>>>(Qb, Kb, Vt, Attn);
    gemm97_kernel<1><<<512, 256, 0, stream>>>(
        Attn, Woutt, b_out, out, nullptr, nullptr, nullptr, 4096, 2048, 2048, 16);
}